// Round 11
// baseline (1841.237 us; speedup 1.0000x reference)
//
#include <hip/hip_runtime.h>
#include <math.h>

// Problem constants
#define N_POS     131072          // 8 * 16*32*32 positions
#define DIM       256
#define K_CODES   512
#define S_SPATIAL 16384           // 16*32*32
#define ZQ_ELEMS  33554432        // 8*256*16384
#define OUT_LOSS  33554432
#define OUT_IDXB  33554433        // idx written as float here
#define OUT_PERP  (33554433 + 131072)

// Workspace layout (bytes) — only ~2.1 KB used (safe for any ws_size)
#define WS_LOSS   0               // double
#define WS_HIST   16              // int[512]
#define WS_E2     2064            // float[512]
#define WS_FIXED  2064            // bytes zeroed (loss + hist)

typedef float sfloat16 __attribute__((ext_vector_type(16)));

// ---------------------------------------------------------------------------
// Kernel 1: codebook squared norms s_e[k], numpy-pairwise replica.
__global__ __launch_bounds__(256) void e2_kernel(const float* __restrict__ e,
                                                 float* __restrict__ e2) {
    int k = blockIdx.x * 256 + threadIdx.x;
    if (k >= K_CODES) return;
    const float* row = e + (size_t)k * DIM;
    float half[2];
#pragma unroll
    for (int h = 0; h < 2; ++h) {
        const float* base = row + h * 128;
        float r[8];
#pragma unroll
        for (int j = 0; j < 8; ++j) {
            float v = base[j];
            r[j] = __fmul_rn(v, v);
        }
        for (int i = 8; i < 128; i += 8) {
#pragma unroll
            for (int j = 0; j < 8; ++j) {
                float v = base[i + j];
                r[j] = __fadd_rn(r[j], __fmul_rn(v, v));
            }
        }
        half[h] = __fadd_rn(__fadd_rn(__fadd_rn(r[0], r[1]), __fadd_rn(r[2], r[3])),
                            __fadd_rn(__fadd_rn(r[4], r[5]), __fadd_rn(r[6], r[7])));
    }
    e2[k] = __fadd_rn(half[0], half[1]);
}

// ---------------------------------------------------------------------------
// Kernel 1b: transpose codebook for pass1. Lane l owns codes k_c = c*64 + l,
// c=0..7. For dim d it reads eTq[d*512 + l*8 + c], i.e. 32 B per lane per d
// as two float4s; the wave reads 2 KB contiguous per d.
__global__ __launch_bounds__(256) void transpose_e(const float* __restrict__ e,
                                                   float* __restrict__ eTq) {
    int t = blockIdx.x * 256 + threadIdx.x;     // t = k*256 + d, coalesced read
    int k = t >> 8;
    int d = t & 255;
    float v = e[t];
    int c = k >> 6;
    int l = k & 63;
    eTq[(d << 9) + (l << 3) + c] = v;
}

// ---------------------------------------------------------------------------
// Kernel 1c: s_z[n] = numpy-pairwise sum of z[n,d]^2. Thread = position,
// lane-coalesced strided loads. Bit-exact: same tree/order as reference.
__global__ __launch_bounds__(256) void sz_kernel(const float* __restrict__ z,
                                                 float* __restrict__ sz) {
    int n = blockIdx.x * 256 + threadIdx.x;
    int b = n >> 14;
    int s = n & (S_SPATIAL - 1);
    const float* zp = z + (size_t)b * (DIM * S_SPATIAL) + s;
    float half[2];
#pragma unroll
    for (int h = 0; h < 2; ++h) {
        const float* base = zp + (size_t)(h * 128) * S_SPATIAL;
        float r[8];
#pragma unroll
        for (int j = 0; j < 8; ++j) {
            float v = base[(size_t)j * S_SPATIAL];
            r[j] = __fmul_rn(v, v);
        }
        for (int i = 8; i < 128; i += 8) {
#pragma unroll
            for (int j = 0; j < 8; ++j) {
                float v = base[(size_t)(i + j) * S_SPATIAL];
                r[j] = __fadd_rn(r[j], __fmul_rn(v, v));
            }
        }
        half[h] = __fadd_rn(__fadd_rn(__fadd_rn(r[0], r[1]), __fadd_rn(r[2], r[3])),
                            __fadd_rn(__fadd_rn(r[4], r[5]), __fadd_rn(r[6], r[7])));
    }
    sz[n] = __fadd_rn(half[0], half[1]);
}

// ---------------------------------------------------------------------------
// Kernel 2: distance + argmin. Block = 256 threads = 4 INDEPENDENT waves;
// each wave owns 16 positions (n0 = blockIdx*64 + wave*16) and covers all
// 512 codes (lane owns C=8: c*64 + lane). Packing 4 waves per workgroup
// lifts the WG-slot occupancy limit (v8: 1-wave WGs -> only 2.4 waves/SIMD;
// occupancy trail 256t=72% / 128t=39% / 64t=30%): VGPR=84 permits 6
// waves/SIMD, and ~5-6 waves cover the ~900 cy HBM-miss latency of the
// scalar z loads. KEY FIX vs v9: wv = threadIdx.x>>6 is wave-uniform but
// divergence analysis can't prove it -> v9 put the z address in VGPRs and
// the "s" asm constraint failed to compile. __builtin_amdgcn_readfirstlane
// asserts uniformity: its result is SGPR-resident, so the n0->zbase->addr
// chain is SALU and s_load_dwordx16 gets a legal scalar address (same asm
// as the v8-PASSED kernel). z via SCALAR pipe: 16 positions at dim d = one
// wave-uniform 64 B line; per FOUR dims one fused asm block (4x
// s_load_dwordx16 at imm offsets + s_waitcnt lgkmcnt(0)) — the async-SMEM
// window never spans C code (v6's failure mode). e-loads: uniform base +
// lane offset, issued before the z-wait. z costs 0 VGPR / 0 LDS; FMAs read
// z as the one legal SGPR operand. Per accumulator the FMA chain ascends d
// — bit-exact numpy replica of the round-8 PASSED math. Argmin tail per
// wave: packed (dist_bits<<32|idx) u64 min over c, 64-lane butterfly,
// first-index ties; histogram fused.
__global__ __launch_bounds__(256, 4) void pass1_dist(const float* __restrict__ z,
                                                     const float* __restrict__ eTq,
                                                     const float* __restrict__ e2,
                                                     const float* __restrict__ sz,
                                                     float* __restrict__ idxf,
                                                     int* __restrict__ ghist) {
    const int lane = threadIdx.x & 63;          // 0..63 within wave
    // wave index, PROVEN uniform to the compiler (SGPR) via readfirstlane:
    const int wv   = __builtin_amdgcn_readfirstlane((int)(threadIdx.x >> 6));
    const int n0   = (blockIdx.x << 6) + (wv << 4);   // 16 positions per wave
    const int b    = n0 >> 14;
    const unsigned long long zbase =
        (unsigned long long)(const void*)(z + (size_t)b * (DIM * S_SPATIAL)
                                            + (n0 & (S_SPATIAL - 1)));

    float szv = sz[n0 + (lane & 15)];           // lane p<16 holds sz[n0+p]

    float se[8];
#pragma unroll
    for (int c = 0; c < 8; ++c) se[c] = e2[(c << 6) + lane];

    float a0[16], a1[16], a2[16], a3[16], a4[16], a5[16], a6[16], a7[16];
#pragma unroll
    for (int p = 0; p < 16; ++p) {
        a0[p] = 0.f; a1[p] = 0.f; a2[p] = 0.f; a3[p] = 0.f;
        a4[p] = 0.f; a5[p] = 0.f; a6[p] = 0.f; a7[p] = 0.f;
    }

    const int eoff = lane << 3;                 // float offset within a dim row

#define FMAS(zv, e0, e1) do {                                    \
        _Pragma("unroll")                                        \
        for (int p = 0; p < 16; ++p) {                           \
            a0[p] = __fmaf_rn((zv)[p], (e0).x, a0[p]);           \
            a1[p] = __fmaf_rn((zv)[p], (e0).y, a1[p]);           \
            a2[p] = __fmaf_rn((zv)[p], (e0).z, a2[p]);           \
            a3[p] = __fmaf_rn((zv)[p], (e0).w, a3[p]);           \
            a4[p] = __fmaf_rn((zv)[p], (e1).x, a4[p]);           \
            a5[p] = __fmaf_rn((zv)[p], (e1).y, a5[p]);           \
            a6[p] = __fmaf_rn((zv)[p], (e1).z, a6[p]);           \
            a7[p] = __fmaf_rn((zv)[p], (e1).w, a7[p]);           \
        }                                                        \
    } while (0)

#pragma unroll 1
    for (int d = 0; d < DIM; d += 4) {
        // e-loads: uniform base + lane offset -> saddr form, SALU bumps.
        const float* eb = eTq + ((size_t)d << 9);
        float4 e0 = *(const float4*)(eb + eoff);
        float4 e1 = *(const float4*)(eb + eoff + 4);
        float4 f0 = *(const float4*)(eb + eoff + 512);
        float4 f1 = *(const float4*)(eb + eoff + 516);
        float4 g0 = *(const float4*)(eb + eoff + 1024);
        float4 g1 = *(const float4*)(eb + eoff + 1028);
        float4 h0 = *(const float4*)(eb + eoff + 1536);
        float4 h1 = *(const float4*)(eb + eoff + 1540);

        sfloat16 zA, zB, zC, zD;                 // live in SGPRs only
        unsigned long long addr = zbase + ((unsigned long long)d << 16);
        asm volatile("s_load_dwordx16 %0, %4, 0x0\n\t"
                     "s_load_dwordx16 %1, %4, 0x10000\n\t"
                     "s_load_dwordx16 %2, %4, 0x20000\n\t"
                     "s_load_dwordx16 %3, %4, 0x30000\n\t"
                     "s_waitcnt lgkmcnt(0)"
                     : "=&s"(zA), "=&s"(zB), "=&s"(zC), "=&s"(zD)
                     : "s"(addr));

        FMAS(zA, e0, e1);                        // dim d   (ascending chain)
        FMAS(zB, f0, f1);                        // dim d+1
        FMAS(zC, g0, g1);                        // dim d+2
        FMAS(zD, h0, h1);                        // dim d+3
    }
#undef FMAS

    // ---- argmin: pack, in-lane min over c (ascending idx), 64-lane
    //      butterfly; lane p keeps position p; fused histogram ----
    unsigned long long myMin = 0xffffffffffffffffull;
#pragma unroll
    for (int p = 0; p < 16; ++p) {
        float szp = __shfl(szv, p);
        float d0 = __fsub_rn(__fadd_rn(szp, se[0]), __fmul_rn(2.0f, a0[p]));
        float d1 = __fsub_rn(__fadd_rn(szp, se[1]), __fmul_rn(2.0f, a1[p]));
        float d2 = __fsub_rn(__fadd_rn(szp, se[2]), __fmul_rn(2.0f, a2[p]));
        float d3 = __fsub_rn(__fadd_rn(szp, se[3]), __fmul_rn(2.0f, a3[p]));
        float d4 = __fsub_rn(__fadd_rn(szp, se[4]), __fmul_rn(2.0f, a4[p]));
        float d5 = __fsub_rn(__fadd_rn(szp, se[5]), __fmul_rn(2.0f, a5[p]));
        float d6 = __fsub_rn(__fadd_rn(szp, se[6]), __fmul_rn(2.0f, a6[p]));
        float d7 = __fsub_rn(__fadd_rn(szp, se[7]), __fmul_rn(2.0f, a7[p]));
        unsigned long long k0 = ((unsigned long long)__float_as_uint(d0) << 32) | (unsigned int)(lane);
        unsigned long long k1 = ((unsigned long long)__float_as_uint(d1) << 32) | (unsigned int)(lane + 64);
        unsigned long long k2 = ((unsigned long long)__float_as_uint(d2) << 32) | (unsigned int)(lane + 128);
        unsigned long long k3 = ((unsigned long long)__float_as_uint(d3) << 32) | (unsigned int)(lane + 192);
        unsigned long long k4 = ((unsigned long long)__float_as_uint(d4) << 32) | (unsigned int)(lane + 256);
        unsigned long long k5 = ((unsigned long long)__float_as_uint(d5) << 32) | (unsigned int)(lane + 320);
        unsigned long long k6 = ((unsigned long long)__float_as_uint(d6) << 32) | (unsigned int)(lane + 384);
        unsigned long long k7 = ((unsigned long long)__float_as_uint(d7) << 32) | (unsigned int)(lane + 448);
        unsigned long long m01 = k1 < k0 ? k1 : k0;
        unsigned long long m23 = k3 < k2 ? k3 : k2;
        unsigned long long m45 = k5 < k4 ? k5 : k4;
        unsigned long long m67 = k7 < k6 ? k7 : k6;
        unsigned long long mA = m23 < m01 ? m23 : m01;
        unsigned long long mB = m67 < m45 ? m67 : m45;
        unsigned long long kmin = mB < mA ? mB : mA;
#pragma unroll
        for (int off = 32; off; off >>= 1) {
            unsigned long long o = __shfl_xor(kmin, off);
            kmin = o < kmin ? o : kmin;
        }
        if (lane == p) myMin = kmin;
    }
    if (lane < 16) {
        int idx = (int)(unsigned int)(myMin & 0xffffffffull);
        idxf[n0 + lane] = (float)idx;
        atomicAdd(&ghist[idx], 1);
    }
}

// ---------------------------------------------------------------------------
// Kernel 4: gather z_q = fl(z + fl(e[idx]-z)) + loss accumulation (double).
__global__ __launch_bounds__(256) void gather_loss(const float* __restrict__ z,
                                                   const float* __restrict__ e,
                                                   const float* __restrict__ idxf,
                                                   float* __restrict__ out,
                                                   double* __restrict__ loss) {
    int t = blockIdx.x * 256 + threadIdx.x;   // 131072 threads total
    int b   = t >> 14;
    int r   = t & 16383;
    int dg  = r >> 12;                        // 0..3 -> d range [dg*64, dg*64+64)
    int sp  = (r & 4095) << 2;                // sp multiple of 4
    int n0  = (b << 14) + sp;

    int k0 = (int)idxf[n0 + 0];
    int k1 = (int)idxf[n0 + 1];
    int k2 = (int)idxf[n0 + 2];
    int k3 = (int)idxf[n0 + 3];
    const float* e0 = e + (size_t)k0 * DIM;
    const float* e1 = e + (size_t)k1 * DIM;
    const float* e2p = e + (size_t)k2 * DIM;
    const float* e3 = e + (size_t)k3 * DIM;

    const float* zb = z + ((size_t)b * DIM << 14) + sp;
    float* ob = out + ((size_t)b * DIM << 14) + sp;

    double acc = 0.0;
    int dend = dg * 64 + 64;
    for (int d0 = dg * 64; d0 < dend; d0 += 4) {
        float4 ev0 = *(const float4*)(e0 + d0);   // components: dd=0..3 for k0
        float4 ev1 = *(const float4*)(e1 + d0);
        float4 ev2 = *(const float4*)(e2p + d0);
        float4 ev3 = *(const float4*)(e3 + d0);
#pragma unroll
        for (int dd = 0; dd < 4; ++dd) {
            size_t off = ((size_t)(d0 + dd) << 14);
            float4 zv = *(const float4*)(zb + off);
            float ea = (dd == 0) ? ev0.x : (dd == 1) ? ev0.y : (dd == 2) ? ev0.z : ev0.w;
            float eb_ = (dd == 0) ? ev1.x : (dd == 1) ? ev1.y : (dd == 2) ? ev1.z : ev1.w;
            float ec = (dd == 0) ? ev2.x : (dd == 1) ? ev2.y : (dd == 2) ? ev2.z : ev2.w;
            float ed = (dd == 0) ? ev3.x : (dd == 1) ? ev3.y : (dd == 2) ? ev3.z : ev3.w;
            float d0f = __fsub_rn(ea, zv.x);
            float d1f = __fsub_rn(eb_, zv.y);
            float d2f = __fsub_rn(ec, zv.z);
            float d3f = __fsub_rn(ed, zv.w);
            float4 ov;
            ov.x = __fadd_rn(zv.x, d0f);
            ov.y = __fadd_rn(zv.y, d1f);
            ov.z = __fadd_rn(zv.z, d2f);
            ov.w = __fadd_rn(zv.w, d3f);
            *(float4*)(ob + off) = ov;
            acc += (double)d0f * (double)d0f;
            acc += (double)d1f * (double)d1f;
            acc += (double)d2f * (double)d2f;
            acc += (double)d3f * (double)d3f;
        }
    }
    // block reduce (4 waves)
    for (int off = 32; off; off >>= 1) acc += __shfl_down(acc, off);
    __shared__ double red[4];
    if ((threadIdx.x & 63) == 0) red[threadIdx.x >> 6] = acc;
    __syncthreads();
    if (threadIdx.x == 0) {
        double tsum = red[0] + red[1] + red[2] + red[3];
        atomicAdd(loss, tsum);
    }
}

// ---------------------------------------------------------------------------
// Kernel 5: finalize vq_loss and perplexity. 1 block, 512 threads.
__global__ __launch_bounds__(512) void finalize_kernel(const int* __restrict__ ghist,
                                                       const double* __restrict__ loss,
                                                       float* __restrict__ out) {
    int k = threadIdx.x;
    double p = (double)ghist[k] / (double)N_POS;
    double t = p * log(p + 1e-10);
    for (int off = 32; off; off >>= 1) t += __shfl_down(t, off);
    __shared__ double red[8];
    if ((k & 63) == 0) red[k >> 6] = t;
    __syncthreads();
    if (k == 0) {
        double sum = 0.0;
        for (int i = 0; i < 8; ++i) sum += red[i];
        double perp = exp(-sum);
        double mse  = (*loss) / (double)ZQ_ELEMS;
        out[OUT_LOSS] = (float)(1.25 * mse);   // codebook + 0.25*commit, same MSE
        out[OUT_PERP] = (float)perp;
    }
}

// ---------------------------------------------------------------------------
extern "C" void kernel_launch(void* const* d_in, const int* in_sizes, int n_in,
                              void* d_out, int out_size, void* d_ws, size_t ws_size,
                              hipStream_t stream) {
    const float* z = (const float*)d_in[0];
    const float* e = (const float*)d_in[1];
    float* out = (float*)d_out;
    char* ws = (char*)d_ws;

    double* loss  = (double*)(ws + WS_LOSS);
    int*    ghist = (int*)(ws + WS_HIST);
    float*  e2    = (float*)(ws + WS_E2);
    float*  idxf  = out + OUT_IDXB;

    // Scratch in the z_q output region (overwritten by gather_loss later,
    // which runs after all readers): eTq = 512 KB, sz = 512 KB.
    float* eTq = (float*)d_out;                     // 131072 floats
    float* szp = (float*)d_out + 131072;            // 131072 floats

    hipMemsetAsync(d_ws, 0, WS_FIXED, stream);      // loss + hist = 0

    e2_kernel      <<<2, 256, 0, stream>>>(e, e2);
    transpose_e    <<<512, 256, 0, stream>>>(e, eTq);
    sz_kernel      <<<N_POS / 256, 256, 0, stream>>>(z, szp);
    pass1_dist     <<<N_POS / 64, 256, 0, stream>>>(z, eTq, e2, szp, idxf, ghist);
    gather_loss    <<<N_POS / 256, 256, 0, stream>>>(z, e, idxf, out, loss);
    finalize_kernel<<<1, 512, 0, stream>>>(ghist, loss, out);
}

// Round 12
// 613.125 us; speedup vs baseline: 3.0030x; 3.0030x over previous
//
#include <hip/hip_runtime.h>
#include <math.h>

// Problem constants
#define N_POS     131072          // 8 * 16*32*32 positions
#define DIM       256
#define K_CODES   512
#define S_SPATIAL 16384           // 16*32*32
#define ZQ_ELEMS  33554432        // 8*256*16384
#define OUT_LOSS  33554432
#define OUT_IDXB  33554433        // idx written as float here
#define OUT_PERP  (33554433 + 131072)

// Workspace layout (bytes) — only ~2.1 KB used (safe for any ws_size)
#define WS_LOSS   0               // double
#define WS_HIST   16              // int[512]
#define WS_E2     2064            // float[512]
#define WS_FIXED  2064            // bytes zeroed (loss + hist)

typedef float sfloat16 __attribute__((ext_vector_type(16)));

// ---------------------------------------------------------------------------
// Kernel 1: codebook squared norms s_e[k], numpy-pairwise replica.
__global__ __launch_bounds__(256) void e2_kernel(const float* __restrict__ e,
                                                 float* __restrict__ e2) {
    int k = blockIdx.x * 256 + threadIdx.x;
    if (k >= K_CODES) return;
    const float* row = e + (size_t)k * DIM;
    float half[2];
#pragma unroll
    for (int h = 0; h < 2; ++h) {
        const float* base = row + h * 128;
        float r[8];
#pragma unroll
        for (int j = 0; j < 8; ++j) {
            float v = base[j];
            r[j] = __fmul_rn(v, v);
        }
        for (int i = 8; i < 128; i += 8) {
#pragma unroll
            for (int j = 0; j < 8; ++j) {
                float v = base[i + j];
                r[j] = __fadd_rn(r[j], __fmul_rn(v, v));
            }
        }
        half[h] = __fadd_rn(__fadd_rn(__fadd_rn(r[0], r[1]), __fadd_rn(r[2], r[3])),
                            __fadd_rn(__fadd_rn(r[4], r[5]), __fadd_rn(r[6], r[7])));
    }
    e2[k] = __fadd_rn(half[0], half[1]);
}

// ---------------------------------------------------------------------------
// Kernel 1b: transpose codebook for pass1. Lane l owns codes k_c = c*64 + l,
// c=0..7. For dim d it reads eTq[d*512 + l*8 + c], i.e. 32 B per lane per d
// as two float4s; the wave reads 2 KB contiguous per d.
__global__ __launch_bounds__(256) void transpose_e(const float* __restrict__ e,
                                                   float* __restrict__ eTq) {
    int t = blockIdx.x * 256 + threadIdx.x;     // t = k*256 + d, coalesced read
    int k = t >> 8;
    int d = t & 255;
    float v = e[t];
    int c = k >> 6;
    int l = k & 63;
    eTq[(d << 9) + (l << 3) + c] = v;
}

// ---------------------------------------------------------------------------
// Kernel 1c: s_z[n] = numpy-pairwise sum of z[n,d]^2. Thread = position,
// lane-coalesced strided loads. Bit-exact: same tree/order as reference.
__global__ __launch_bounds__(256) void sz_kernel(const float* __restrict__ z,
                                                 float* __restrict__ sz) {
    int n = blockIdx.x * 256 + threadIdx.x;
    int b = n >> 14;
    int s = n & (S_SPATIAL - 1);
    const float* zp = z + (size_t)b * (DIM * S_SPATIAL) + s;
    float half[2];
#pragma unroll
    for (int h = 0; h < 2; ++h) {
        const float* base = zp + (size_t)(h * 128) * S_SPATIAL;
        float r[8];
#pragma unroll
        for (int j = 0; j < 8; ++j) {
            float v = base[(size_t)j * S_SPATIAL];
            r[j] = __fmul_rn(v, v);
        }
        for (int i = 8; i < 128; i += 8) {
#pragma unroll
            for (int j = 0; j < 8; ++j) {
                float v = base[(size_t)(i + j) * S_SPATIAL];
                r[j] = __fadd_rn(r[j], __fmul_rn(v, v));
            }
        }
        half[h] = __fadd_rn(__fadd_rn(__fadd_rn(r[0], r[1]), __fadd_rn(r[2], r[3])),
                            __fadd_rn(__fadd_rn(r[4], r[5]), __fadd_rn(r[6], r[7])));
    }
    sz[n] = __fadd_rn(half[0], half[1]);
}

// ---------------------------------------------------------------------------
// Kernel 2: distance + argmin. Block = 256 threads = 4 INDEPENDENT waves;
// each wave owns 16 positions (n0 = blockIdx*64 + wave*16) and covers all
// 512 codes (lane owns C=8: c*64 + lane). 4-wave workgroups lift the
// WG-slot occupancy limit (1-wave WGs in v8 -> only 2.4 waves/SIMD).
// LAUNCH BOUNDS: (256, 3) NOT (256, 4) — v10's (256,4) capped the unified
// register budget at 128/thread, below the ~150-reg working set (128 accs),
// so the allocator spilled accumulators to scratch: VGPR 84->64, WRITE_SIZE
// 16 MB -> 5.6 GB, pass1 370 -> 1615 us. Cap 170 (=v7/v8's proven budget)
// keeps the accs in registers; occupancy is then VGPR-bound (~6 waves/SIMD
// at 84 VGPR), giving the latency hiding v8 lacked. wv uniformity asserted
// via readfirstlane (v9's compile fix): n0->zbase->addr stays SALU so the
// "s" constraints bind. z via SCALAR pipe: 16 positions at dim d = one
// wave-uniform 64 B line; per FOUR dims one fused asm block (4x
// s_load_dwordx16 at imm offsets + s_waitcnt lgkmcnt(0)) — async-SMEM
// window never spans C code (v6's failure mode). e-loads: uniform base +
// lane offset, issued before the z-wait. z costs 0 VGPR / 0 LDS; FMAs read
// z as the one legal SGPR operand. Per accumulator the FMA chain ascends d
// — bit-exact numpy replica of the round-10 PASSED math. Argmin tail per
// wave: packed (dist_bits<<32|idx) u64 min over c, 64-lane butterfly,
// first-index ties; histogram fused.
__global__ __launch_bounds__(256, 3) void pass1_dist(const float* __restrict__ z,
                                                     const float* __restrict__ eTq,
                                                     const float* __restrict__ e2,
                                                     const float* __restrict__ sz,
                                                     float* __restrict__ idxf,
                                                     int* __restrict__ ghist) {
    const int lane = threadIdx.x & 63;          // 0..63 within wave
    // wave index, PROVEN uniform to the compiler (SGPR) via readfirstlane:
    const int wv   = __builtin_amdgcn_readfirstlane((int)(threadIdx.x >> 6));
    const int n0   = (blockIdx.x << 6) + (wv << 4);   // 16 positions per wave
    const int b    = n0 >> 14;
    const unsigned long long zbase =
        (unsigned long long)(const void*)(z + (size_t)b * (DIM * S_SPATIAL)
                                            + (n0 & (S_SPATIAL - 1)));

    float szv = sz[n0 + (lane & 15)];           // lane p<16 holds sz[n0+p]

    float se[8];
#pragma unroll
    for (int c = 0; c < 8; ++c) se[c] = e2[(c << 6) + lane];

    float a0[16], a1[16], a2[16], a3[16], a4[16], a5[16], a6[16], a7[16];
#pragma unroll
    for (int p = 0; p < 16; ++p) {
        a0[p] = 0.f; a1[p] = 0.f; a2[p] = 0.f; a3[p] = 0.f;
        a4[p] = 0.f; a5[p] = 0.f; a6[p] = 0.f; a7[p] = 0.f;
    }

    const int eoff = lane << 3;                 // float offset within a dim row

#define FMAS(zv, e0, e1) do {                                    \
        _Pragma("unroll")                                        \
        for (int p = 0; p < 16; ++p) {                           \
            a0[p] = __fmaf_rn((zv)[p], (e0).x, a0[p]);           \
            a1[p] = __fmaf_rn((zv)[p], (e0).y, a1[p]);           \
            a2[p] = __fmaf_rn((zv)[p], (e0).z, a2[p]);           \
            a3[p] = __fmaf_rn((zv)[p], (e0).w, a3[p]);           \
            a4[p] = __fmaf_rn((zv)[p], (e1).x, a4[p]);           \
            a5[p] = __fmaf_rn((zv)[p], (e1).y, a5[p]);           \
            a6[p] = __fmaf_rn((zv)[p], (e1).z, a6[p]);           \
            a7[p] = __fmaf_rn((zv)[p], (e1).w, a7[p]);           \
        }                                                        \
    } while (0)

#pragma unroll 1
    for (int d = 0; d < DIM; d += 4) {
        // e-loads: uniform base + lane offset -> saddr form, SALU bumps.
        const float* eb = eTq + ((size_t)d << 9);
        float4 e0 = *(const float4*)(eb + eoff);
        float4 e1 = *(const float4*)(eb + eoff + 4);
        float4 f0 = *(const float4*)(eb + eoff + 512);
        float4 f1 = *(const float4*)(eb + eoff + 516);
        float4 g0 = *(const float4*)(eb + eoff + 1024);
        float4 g1 = *(const float4*)(eb + eoff + 1028);
        float4 h0 = *(const float4*)(eb + eoff + 1536);
        float4 h1 = *(const float4*)(eb + eoff + 1540);

        sfloat16 zA, zB, zC, zD;                 // live in SGPRs only
        unsigned long long addr = zbase + ((unsigned long long)d << 16);
        asm volatile("s_load_dwordx16 %0, %4, 0x0\n\t"
                     "s_load_dwordx16 %1, %4, 0x10000\n\t"
                     "s_load_dwordx16 %2, %4, 0x20000\n\t"
                     "s_load_dwordx16 %3, %4, 0x30000\n\t"
                     "s_waitcnt lgkmcnt(0)"
                     : "=&s"(zA), "=&s"(zB), "=&s"(zC), "=&s"(zD)
                     : "s"(addr));

        FMAS(zA, e0, e1);                        // dim d   (ascending chain)
        FMAS(zB, f0, f1);                        // dim d+1
        FMAS(zC, g0, g1);                        // dim d+2
        FMAS(zD, h0, h1);                        // dim d+3
    }
#undef FMAS

    // ---- argmin: pack, in-lane min over c (ascending idx), 64-lane
    //      butterfly; lane p keeps position p; fused histogram ----
    unsigned long long myMin = 0xffffffffffffffffull;
#pragma unroll
    for (int p = 0; p < 16; ++p) {
        float szp = __shfl(szv, p);
        float d0 = __fsub_rn(__fadd_rn(szp, se[0]), __fmul_rn(2.0f, a0[p]));
        float d1 = __fsub_rn(__fadd_rn(szp, se[1]), __fmul_rn(2.0f, a1[p]));
        float d2 = __fsub_rn(__fadd_rn(szp, se[2]), __fmul_rn(2.0f, a2[p]));
        float d3 = __fsub_rn(__fadd_rn(szp, se[3]), __fmul_rn(2.0f, a3[p]));
        float d4 = __fsub_rn(__fadd_rn(szp, se[4]), __fmul_rn(2.0f, a4[p]));
        float d5 = __fsub_rn(__fadd_rn(szp, se[5]), __fmul_rn(2.0f, a5[p]));
        float d6 = __fsub_rn(__fadd_rn(szp, se[6]), __fmul_rn(2.0f, a6[p]));
        float d7 = __fsub_rn(__fadd_rn(szp, se[7]), __fmul_rn(2.0f, a7[p]));
        unsigned long long k0 = ((unsigned long long)__float_as_uint(d0) << 32) | (unsigned int)(lane);
        unsigned long long k1 = ((unsigned long long)__float_as_uint(d1) << 32) | (unsigned int)(lane + 64);
        unsigned long long k2 = ((unsigned long long)__float_as_uint(d2) << 32) | (unsigned int)(lane + 128);
        unsigned long long k3 = ((unsigned long long)__float_as_uint(d3) << 32) | (unsigned int)(lane + 192);
        unsigned long long k4 = ((unsigned long long)__float_as_uint(d4) << 32) | (unsigned int)(lane + 256);
        unsigned long long k5 = ((unsigned long long)__float_as_uint(d5) << 32) | (unsigned int)(lane + 320);
        unsigned long long k6 = ((unsigned long long)__float_as_uint(d6) << 32) | (unsigned int)(lane + 384);
        unsigned long long k7 = ((unsigned long long)__float_as_uint(d7) << 32) | (unsigned int)(lane + 448);
        unsigned long long m01 = k1 < k0 ? k1 : k0;
        unsigned long long m23 = k3 < k2 ? k3 : k2;
        unsigned long long m45 = k5 < k4 ? k5 : k4;
        unsigned long long m67 = k7 < k6 ? k7 : k6;
        unsigned long long mA = m23 < m01 ? m23 : m01;
        unsigned long long mB = m67 < m45 ? m67 : m45;
        unsigned long long kmin = mB < mA ? mB : mA;
#pragma unroll
        for (int off = 32; off; off >>= 1) {
            unsigned long long o = __shfl_xor(kmin, off);
            kmin = o < kmin ? o : kmin;
        }
        if (lane == p) myMin = kmin;
    }
    if (lane < 16) {
        int idx = (int)(unsigned int)(myMin & 0xffffffffull);
        idxf[n0 + lane] = (float)idx;
        atomicAdd(&ghist[idx], 1);
    }
}

// ---------------------------------------------------------------------------
// Kernel 4: gather z_q = fl(z + fl(e[idx]-z)) + loss accumulation (double).
__global__ __launch_bounds__(256) void gather_loss(const float* __restrict__ z,
                                                   const float* __restrict__ e,
                                                   const float* __restrict__ idxf,
                                                   float* __restrict__ out,
                                                   double* __restrict__ loss) {
    int t = blockIdx.x * 256 + threadIdx.x;   // 131072 threads total
    int b   = t >> 14;
    int r   = t & 16383;
    int dg  = r >> 12;                        // 0..3 -> d range [dg*64, dg*64+64)
    int sp  = (r & 4095) << 2;                // sp multiple of 4
    int n0  = (b << 14) + sp;

    int k0 = (int)idxf[n0 + 0];
    int k1 = (int)idxf[n0 + 1];
    int k2 = (int)idxf[n0 + 2];
    int k3 = (int)idxf[n0 + 3];
    const float* e0 = e + (size_t)k0 * DIM;
    const float* e1 = e + (size_t)k1 * DIM;
    const float* e2p = e + (size_t)k2 * DIM;
    const float* e3 = e + (size_t)k3 * DIM;

    const float* zb = z + ((size_t)b * DIM << 14) + sp;
    float* ob = out + ((size_t)b * DIM << 14) + sp;

    double acc = 0.0;
    int dend = dg * 64 + 64;
    for (int d0 = dg * 64; d0 < dend; d0 += 4) {
        float4 ev0 = *(const float4*)(e0 + d0);   // components: dd=0..3 for k0
        float4 ev1 = *(const float4*)(e1 + d0);
        float4 ev2 = *(const float4*)(e2p + d0);
        float4 ev3 = *(const float4*)(e3 + d0);
#pragma unroll
        for (int dd = 0; dd < 4; ++dd) {
            size_t off = ((size_t)(d0 + dd) << 14);
            float4 zv = *(const float4*)(zb + off);
            float ea = (dd == 0) ? ev0.x : (dd == 1) ? ev0.y : (dd == 2) ? ev0.z : ev0.w;
            float eb_ = (dd == 0) ? ev1.x : (dd == 1) ? ev1.y : (dd == 2) ? ev1.z : ev1.w;
            float ec = (dd == 0) ? ev2.x : (dd == 1) ? ev2.y : (dd == 2) ? ev2.z : ev2.w;
            float ed = (dd == 0) ? ev3.x : (dd == 1) ? ev3.y : (dd == 2) ? ev3.z : ev3.w;
            float d0f = __fsub_rn(ea, zv.x);
            float d1f = __fsub_rn(eb_, zv.y);
            float d2f = __fsub_rn(ec, zv.z);
            float d3f = __fsub_rn(ed, zv.w);
            float4 ov;
            ov.x = __fadd_rn(zv.x, d0f);
            ov.y = __fadd_rn(zv.y, d1f);
            ov.z = __fadd_rn(zv.z, d2f);
            ov.w = __fadd_rn(zv.w, d3f);
            *(float4*)(ob + off) = ov;
            acc += (double)d0f * (double)d0f;
            acc += (double)d1f * (double)d1f;
            acc += (double)d2f * (double)d2f;
            acc += (double)d3f * (double)d3f;
        }
    }
    // block reduce (4 waves)
    for (int off = 32; off; off >>= 1) acc += __shfl_down(acc, off);
    __shared__ double red[4];
    if ((threadIdx.x & 63) == 0) red[threadIdx.x >> 6] = acc;
    __syncthreads();
    if (threadIdx.x == 0) {
        double tsum = red[0] + red[1] + red[2] + red[3];
        atomicAdd(loss, tsum);
    }
}

// ---------------------------------------------------------------------------
// Kernel 5: finalize vq_loss and perplexity. 1 block, 512 threads.
__global__ __launch_bounds__(512) void finalize_kernel(const int* __restrict__ ghist,
                                                       const double* __restrict__ loss,
                                                       float* __restrict__ out) {
    int k = threadIdx.x;
    double p = (double)ghist[k] / (double)N_POS;
    double t = p * log(p + 1e-10);
    for (int off = 32; off; off >>= 1) t += __shfl_down(t, off);
    __shared__ double red[8];
    if ((k & 63) == 0) red[k >> 6] = t;
    __syncthreads();
    if (k == 0) {
        double sum = 0.0;
        for (int i = 0; i < 8; ++i) sum += red[i];
        double perp = exp(-sum);
        double mse  = (*loss) / (double)ZQ_ELEMS;
        out[OUT_LOSS] = (float)(1.25 * mse);   // codebook + 0.25*commit, same MSE
        out[OUT_PERP] = (float)perp;
    }
}

// ---------------------------------------------------------------------------
extern "C" void kernel_launch(void* const* d_in, const int* in_sizes, int n_in,
                              void* d_out, int out_size, void* d_ws, size_t ws_size,
                              hipStream_t stream) {
    const float* z = (const float*)d_in[0];
    const float* e = (const float*)d_in[1];
    float* out = (float*)d_out;
    char* ws = (char*)d_ws;

    double* loss  = (double*)(ws + WS_LOSS);
    int*    ghist = (int*)(ws + WS_HIST);
    float*  e2    = (float*)(ws + WS_E2);
    float*  idxf  = out + OUT_IDXB;

    // Scratch in the z_q output region (overwritten by gather_loss later,
    // which runs after all readers): eTq = 512 KB, sz = 512 KB.
    float* eTq = (float*)d_out;                     // 131072 floats
    float* szp = (float*)d_out + 131072;            // 131072 floats

    hipMemsetAsync(d_ws, 0, WS_FIXED, stream);      // loss + hist = 0

    e2_kernel      <<<2, 256, 0, stream>>>(e, e2);
    transpose_e    <<<512, 256, 0, stream>>>(e, eTq);
    sz_kernel      <<<N_POS / 256, 256, 0, stream>>>(z, szp);
    pass1_dist     <<<N_POS / 64, 256, 0, stream>>>(z, eTq, e2, szp, idxf, ghist);
    gather_loss    <<<N_POS / 256, 256, 0, stream>>>(z, e, idxf, out, loss);
    finalize_kernel<<<1, 512, 0, stream>>>(ghist, loss, out);
}